// Round 1
// baseline (51.352 us; speedup 1.0000x reference)
//
#include <hip/hip_runtime.h>

// RandomShift (DrQ-style) for x[512,9,84,84] f32, shift[512,2] int32 in [0,8].
// Math (derived from reference): out[n,c,i,j] = bilinear sample of zero-padded
// x at (row = j*91/83 + shift[n,1], col = i*91/83 + shift[n,0]) in padded
// coords; tap value nonzero only when padded coord in [4,88).
// One block per (n,c) plane; plane staged TRANSPOSED into LDS (stride 85,
// conflict-free both ways); each thread emits a float4 of 4 consecutive j.

constexpr int HW     = 84;
constexpr int LDSW   = 85;           // pad: gcd(85,32)=1 -> no bank conflicts
constexpr int NPLANE = HW * HW;      // 7056
constexpr int NQUAD  = NPLANE / 4;   // 1764 (84 % 4 == 0: quads never cross rows)

__device__ __forceinline__ int iclamp(int v, int lo, int hi) {
    return v < lo ? lo : (v > hi ? hi : v);
}

__global__ __launch_bounds__(256) void rshift_kernel(
    const float* __restrict__ x,
    const int*   __restrict__ shift,
    float*       __restrict__ out)
{
    __shared__ float lds[HW * LDSW];         // lds[col*LDSW + row] (transposed)

    const int plane = blockIdx.x;            // n*9 + c
    const int n     = plane / 9;
    const float s0  = (float)shift[2 * n];       // applied along i (columns)
    const float s1  = (float)shift[2 * n + 1];   // applied along j (rows)
    const float* __restrict__ src = x   + (size_t)plane * NPLANE;
    float*       __restrict__ dst = out + (size_t)plane * NPLANE;
    const int t = threadIdx.x;
    const float R = 91.0f / 83.0f;

    // ---- stage plane into LDS, transposed ----
    // scalar dword loads (wave of 64 consecutive dwords = fully coalesced);
    // LDS writes stride 85 floats -> conflict-free.
    #pragma unroll
    for (int k = 0; k < 28; ++k) {
        int idx = t + k * 256;
        if (idx < NPLANE) {
            int row = idx / HW;
            int col = idx - row * HW;
            lds[col * LDSW + row] = src[idx];
        }
    }
    __syncthreads();

    // ---- compute: 4 consecutive j per thread, float4 store ----
    #pragma unroll
    for (int k = 0; k < 7; ++k) {
        int q = t + k * 256;
        if (q >= NQUAD) break;
        int i  = q / 21;                 // 21 quads per output row
        int jb = (q - i * 21) * 4;

        float fx  = fmaf((float)i, R, s0);
        int   x0  = (int)fx;             // fx >= 0 always
        float wx1 = fx - (float)x0;
        float wx0 = 1.0f - wx1;
        int   u0  = x0 - 4;              // image-space column
        int   u1  = x0 - 3;
        float mx0 = ((unsigned)u0 < 84u) ? wx0 : 0.0f;
        float mx1 = ((unsigned)u1 < 84u) ? wx1 : 0.0f;
        int   cu0 = iclamp(u0, 0, 83) * LDSW;
        int   cu1 = iclamp(u1, 0, 83) * LDSW;

        float r[4];
        #pragma unroll
        for (int e = 0; e < 4; ++e) {
            float fy  = fmaf((float)(jb + e), R, s1);
            int   y0  = (int)fy;
            float wy1 = fy - (float)y0;
            float wy0 = 1.0f - wy1;
            int   t0  = y0 - 4;          // image-space row
            int   t1  = y0 - 3;
            float my0 = ((unsigned)t0 < 84u) ? wy0 : 0.0f;
            float my1 = ((unsigned)t1 < 84u) ? wy1 : 0.0f;
            int   ct0 = iclamp(t0, 0, 83);
            int   ct1 = iclamp(t1, 0, 83);
            float v00 = lds[cu0 + ct0];
            float v01 = lds[cu0 + ct1];
            float v10 = lds[cu1 + ct0];
            float v11 = lds[cu1 + ct1];
            r[e] = my0 * fmaf(mx0, v00, mx1 * v10)
                 + my1 * fmaf(mx0, v01, mx1 * v11);
        }
        float4 o;
        o.x = r[0]; o.y = r[1]; o.z = r[2]; o.w = r[3];
        *reinterpret_cast<float4*>(dst + (size_t)q * 4) = o;
    }
}

extern "C" void kernel_launch(void* const* d_in, const int* in_sizes, int n_in,
                              void* d_out, int out_size, void* d_ws, size_t ws_size,
                              hipStream_t stream) {
    const float* x     = (const float*)d_in[0];
    const int*   shift = (const int*)d_in[1];
    float*       out   = (float*)d_out;
    const int planes = 512 * 9;   // N*C
    rshift_kernel<<<planes, 256, 0, stream>>>(x, shift, out);
}

// Round 3
// 47.506 us; speedup vs baseline: 1.0810x; 1.0810x over previous
//
#include <hip/hip_runtime.h>

// RandomShift (DrQ-style) for x[512,9,84,84] f32, shift[512,2] int32 in [0,8].
// out[n,c,i,j] = bilinear sample of zero-padded x at
// (row = j*91/83 + shift[n,1], col = i*91/83 + shift[n,0]) in padded coords;
// taps nonzero only when padded coord in [4,88).
//
// One block per (n,c) plane; plane staged TRANSPOSED into LDS (stride 85).
// Lane remap: lane = jq + 21*i_sub (jq = j-quad 0..20, i_sub = 0..2, lane 63
// idle). Within one ds_read, jq strides ~4.4 floats (spans >2 bank wraps ->
// ~distinct banks) and i_sub shifts banks by {0,21,10} -> ~2-way conflicts
// (free). y-params depend only on jq -> hoisted out of the k-loop.

constexpr int HW     = 84;
constexpr int LDSW   = 85;           // gcd(85,32)=1 -> conflict-free staging
constexpr int NPLANE = HW * HW;      // 7056

typedef float vfloat4 __attribute__((ext_vector_type(4)));  // clang-native

__device__ __forceinline__ int iclamp(int v, int lo, int hi) {
    return v < lo ? lo : (v > hi ? hi : v);
}

__global__ __launch_bounds__(256) void rshift_kernel(
    const float* __restrict__ x,
    const int*   __restrict__ shift,
    float*       __restrict__ out)
{
    __shared__ float lds[HW * LDSW];         // lds[col*LDSW + row] (transposed)

    const int plane = blockIdx.x;            // n*9 + c
    const int n     = plane / 9;
    const float s0  = (float)shift[2 * n];       // along i (columns)
    const float s1  = (float)shift[2 * n + 1];   // along j (rows)
    const float* __restrict__ src = x   + (size_t)plane * NPLANE;
    float*       __restrict__ dst = out + (size_t)plane * NPLANE;
    const int t = threadIdx.x;
    const float R = 91.0f / 83.0f;

    // ---- per-thread y-params (loop-invariant): lane -> (jq, i_sub) ----
    const int lane = t & 63;
    const int wv   = t >> 6;
    const int jq   = lane % 21;          // j-quad within row
    const int isub = lane / 21;          // 0..2 active, 3 -> idle lane

    float my0[4], my1[4];
    int   ct0[4], ct1[4];
    #pragma unroll
    for (int e = 0; e < 4; ++e) {
        float fy  = fmaf((float)(4 * jq + e), R, s1);
        int   y0  = (int)fy;             // fy >= 0
        float wy1 = fy - (float)y0;
        float wy0 = 1.0f - wy1;
        int   t0  = y0 - 4;
        int   t1  = y0 - 3;
        my0[e] = ((unsigned)t0 < 84u) ? wy0 : 0.0f;
        my1[e] = ((unsigned)t1 < 84u) ? wy1 : 0.0f;
        ct0[e] = iclamp(t0, 0, 83);
        ct1[e] = iclamp(t1, 0, 83);
    }

    // ---- stage plane into LDS, transposed ----
    // consecutive lanes: consecutive cols -> LDS write stride 85 (bank
    // stride 21, gcd(21,32)=1) -> conflict-free; global reads coalesced.
    #pragma unroll
    for (int k = 0; k < 28; ++k) {
        int idx = t + k * 256;
        if (idx < NPLANE) {
            int row = idx / HW;
            int col = idx - row * HW;
            lds[col * LDSW + row] = src[idx];
        }
    }
    __syncthreads();

    // ---- compute: 7 iterations x (3 i-rows per wave), float4 store ----
    if (isub < 3) {
        #pragma unroll
        for (int k = 0; k < 7; ++k) {
            int   i   = k * 12 + wv * 3 + isub;
            float fx  = fmaf((float)i, R, s0);
            int   x0  = (int)fx;
            float wx1 = fx - (float)x0;
            float wx0 = 1.0f - wx1;
            int   u0  = x0 - 4;
            int   u1  = x0 - 3;
            float mx0 = ((unsigned)u0 < 84u) ? wx0 : 0.0f;
            float mx1 = ((unsigned)u1 < 84u) ? wx1 : 0.0f;
            int   cu0 = iclamp(u0, 0, 83) * LDSW;
            int   cu1 = iclamp(u1, 0, 83) * LDSW;

            vfloat4 o;
            #pragma unroll
            for (int e = 0; e < 4; ++e) {
                float v00 = lds[cu0 + ct0[e]];
                float v01 = lds[cu0 + ct1[e]];
                float v10 = lds[cu1 + ct0[e]];
                float v11 = lds[cu1 + ct1[e]];
                o[e] = my0[e] * fmaf(mx0, v00, mx1 * v10)
                     + my1[e] * fmaf(mx0, v01, mx1 * v11);
            }
            __builtin_nontemporal_store(
                o, reinterpret_cast<vfloat4*>(dst + (size_t)i * HW + 4 * jq));
        }
    }
}

extern "C" void kernel_launch(void* const* d_in, const int* in_sizes, int n_in,
                              void* d_out, int out_size, void* d_ws, size_t ws_size,
                              hipStream_t stream) {
    const float* x     = (const float*)d_in[0];
    const int*   shift = (const int*)d_in[1];
    float*       out   = (float*)d_out;
    const int planes = 512 * 9;   // N*C
    rshift_kernel<<<planes, 256, 0, stream>>>(x, shift, out);
}